// Round 1
// baseline (2206.583 us; speedup 1.0000x reference)
//
#include <hip/hip_runtime.h>
#include <hip/hip_bf16.h>
#include <stdint.h>

// Problem constants (B=8, T=4096, Zc=512, D=256, K=8192)
#define M_TOT 32768
#define ZC 512
#define DD 256
#define KCODES 8192

// Workspace layout (bytes)
#define OFF_H    0ull                       // h: M_TOT*DD f32 = 32 MB
#define OFF_HH   33554432ull                // hh: M_TOT f32
#define OFF_EE   (OFF_HH + 131072ull)       // ee: KCODES f32
#define OFF_KEYS (OFF_EE + 32768ull)        // keys: M_TOT u64
#define OFF_LOSS (OFF_KEYS + 262144ull)     // loss accumulator: 1 f32

// ---------------------------------------------------------------------------
// K1: h[M,256] = x[M,512] @ W[512,256] + b   (fp32, 64x64 tile, 4x4/thread)
// ---------------------------------------------------------------------------
__global__ __launch_bounds__(256) void k_gemm1(const float* __restrict__ x,
                                               const float* __restrict__ W,
                                               const float* __restrict__ b,
                                               float* __restrict__ h) {
    __shared__ float sA[16 * 68];  // [k][row], pad 68 to break bank conflicts
    __shared__ float sB[16 * 68];  // [k][n]
    const int tx = threadIdx.x, ty = threadIdx.y;
    const int tid = ty * 16 + tx;
    const int m0 = blockIdx.y * 64;
    const int n0 = blockIdx.x * 64;

    const int lrowA = tid >> 2, kqA = tid & 3;   // x load: 64 rows x 4 float4
    const int kB = tid >> 4,   nqB = tid & 15;   // W load: 16 k x 16 float4

    float acc[4][4] = {};

    for (int kb = 0; kb < ZC; kb += 16) {
        float4 va = *(const float4*)&x[(size_t)(m0 + lrowA) * ZC + kb + kqA * 4];
        float4 vb = *(const float4*)&W[(size_t)(kb + kB) * DD + n0 + nqB * 4];
        __syncthreads();
        sA[(kqA * 4 + 0) * 68 + lrowA] = va.x;
        sA[(kqA * 4 + 1) * 68 + lrowA] = va.y;
        sA[(kqA * 4 + 2) * 68 + lrowA] = va.z;
        sA[(kqA * 4 + 3) * 68 + lrowA] = va.w;
        sB[kB * 68 + nqB * 4 + 0] = vb.x;
        sB[kB * 68 + nqB * 4 + 1] = vb.y;
        sB[kB * 68 + nqB * 4 + 2] = vb.z;
        sB[kB * 68 + nqB * 4 + 3] = vb.w;
        __syncthreads();
#pragma unroll
        for (int k = 0; k < 16; ++k) {
            float4 a4 = *(const float4*)&sA[k * 68 + ty * 4];
            float4 b4 = *(const float4*)&sB[k * 68 + tx * 4];
            float av[4] = {a4.x, a4.y, a4.z, a4.w};
            float bv[4] = {b4.x, b4.y, b4.z, b4.w};
#pragma unroll
            for (int i = 0; i < 4; ++i)
#pragma unroll
                for (int j = 0; j < 4; ++j)
                    acc[i][j] = fmaf(av[i], bv[j], acc[i][j]);
        }
    }
#pragma unroll
    for (int i = 0; i < 4; ++i) {
        const size_t row = (size_t)(m0 + ty * 4 + i);
#pragma unroll
        for (int j = 0; j < 4; ++j) {
            const int n = n0 + tx * 4 + j;
            h[row * DD + n] = acc[i][j] + b[n];
        }
    }
}

// ---------------------------------------------------------------------------
// Row squared-norms (ncols fixed = 256, one block per row)
// ---------------------------------------------------------------------------
__global__ __launch_bounds__(256) void k_rownorm(const float* __restrict__ a,
                                                 float* __restrict__ out) {
    const int row = blockIdx.x;
    const int tid = threadIdx.x;
    float v = a[(size_t)row * DD + tid];
    float s = v * v;
#pragma unroll
    for (int off = 32; off; off >>= 1) s += __shfl_down(s, off);
    __shared__ float wsum[4];
    if ((tid & 63) == 0) wsum[tid >> 6] = s;
    __syncthreads();
    if (tid == 0) out[row] = (wsum[0] + wsum[1]) + (wsum[2] + wsum[3]);
}

// ---------------------------------------------------------------------------
// Init keys to max, loss to 0 (avoid relying on memset semantics in capture)
// ---------------------------------------------------------------------------
__global__ __launch_bounds__(256) void k_init(unsigned long long* __restrict__ keys,
                                              float* __restrict__ loss) {
    const int i = blockIdx.x * 256 + threadIdx.x;
    if (i < M_TOT) keys[i] = ~0ull;
    if (i == M_TOT) *loss = 0.0f;
}

// ---------------------------------------------------------------------------
// K2: fused distance + argmin. 128 rows x 128 codes per block, 8x8/thread.
// d(r,c) = (hh[r]+ee[c]) - 2*dot(h[r],cb[c]); running min as packed u64 key
// (float bits << 32 | code index) -> atomicMin gives np.argmin tie-break.
// ---------------------------------------------------------------------------
__global__ __launch_bounds__(256) void k_dist_argmin(const float* __restrict__ h,
                                                     const float* __restrict__ cb,
                                                     const float* __restrict__ hh,
                                                     const float* __restrict__ ee,
                                                     unsigned long long* __restrict__ keys) {
    __shared__ float sA[8 * 132];  // [k][row], pad 132 (16B-aligned rows)
    __shared__ float sB[8 * 132];  // [k][code]
    __shared__ unsigned long long red[128 * 16];

    const int tx = threadIdx.x, ty = threadIdx.y;
    const int tid = ty * 16 + tx;
    const int m0 = blockIdx.y * 128;
    const int c0 = blockIdx.x * 128;

    const int lrow = tid >> 1, kq = tid & 1;  // 128 rows x 2 float4 (8 k)

    float acc[8][8] = {};

    for (int kb = 0; kb < DD; kb += 8) {
        float4 va = *(const float4*)&h [(size_t)(m0 + lrow) * DD + kb + kq * 4];
        float4 vb = *(const float4*)&cb[(size_t)(c0 + lrow) * DD + kb + kq * 4];
        __syncthreads();
        sA[(kq * 4 + 0) * 132 + lrow] = va.x;
        sA[(kq * 4 + 1) * 132 + lrow] = va.y;
        sA[(kq * 4 + 2) * 132 + lrow] = va.z;
        sA[(kq * 4 + 3) * 132 + lrow] = va.w;
        sB[(kq * 4 + 0) * 132 + lrow] = vb.x;
        sB[(kq * 4 + 1) * 132 + lrow] = vb.y;
        sB[(kq * 4 + 2) * 132 + lrow] = vb.z;
        sB[(kq * 4 + 3) * 132 + lrow] = vb.w;
        __syncthreads();
#pragma unroll
        for (int k = 0; k < 8; ++k) {
            const float* ap = &sA[k * 132 + ty * 8];
            const float* bp = &sB[k * 132 + tx * 8];
            float4 alo = *(const float4*)(ap);
            float4 ahi = *(const float4*)(ap + 4);
            float4 blo = *(const float4*)(bp);
            float4 bhi = *(const float4*)(bp + 4);
            float av[8] = {alo.x, alo.y, alo.z, alo.w, ahi.x, ahi.y, ahi.z, ahi.w};
            float bv[8] = {blo.x, blo.y, blo.z, blo.w, bhi.x, bhi.y, bhi.z, bhi.w};
#pragma unroll
            for (int i = 0; i < 8; ++i)
#pragma unroll
                for (int j = 0; j < 8; ++j)
                    acc[i][j] = fmaf(av[i], bv[j], acc[i][j]);
        }
    }

    // Epilogue: per-thread min over 8 codes per row, then cross-thread.
    float eev[8];
#pragma unroll
    for (int j = 0; j < 8; ++j) eev[j] = ee[c0 + tx * 8 + j];
#pragma unroll
    for (int i = 0; i < 8; ++i) {
        const float hv = hh[m0 + ty * 8 + i];
        unsigned long long best = ~0ull;
#pragma unroll
        for (int j = 0; j < 8; ++j) {
            // Match numpy rounding order: (||h||^2 + ||e||^2) - 2*he
            const float d = (hv + eev[j]) - 2.0f * acc[i][j];
            const unsigned long long key =
                ((unsigned long long)__float_as_uint(d) << 32) |
                (unsigned long long)(unsigned)(c0 + tx * 8 + j);
            if (key < best) best = key;
        }
        red[(ty * 8 + i) * 16 + tx] = best;
    }
    __syncthreads();
    if (tid < 128) {
        unsigned long long best = red[tid * 16];
#pragma unroll
        for (int t = 1; t < 16; ++t) {
            const unsigned long long k2 = red[tid * 16 + t];
            if (k2 < best) best = k2;
        }
        atomicMin(&keys[m0 + tid], best);
    }
}

// ---------------------------------------------------------------------------
// K3: gather zq, write quant output, accumulate sum((zq-h)^2)
// ---------------------------------------------------------------------------
__global__ __launch_bounds__(256) void k_gather_loss(const float* __restrict__ h,
                                                     const float* __restrict__ cb,
                                                     const unsigned long long* __restrict__ keys,
                                                     float* __restrict__ out,
                                                     float* __restrict__ loss) {
    const int row = blockIdx.x;
    const int tid = threadIdx.x;
    const unsigned idx = (unsigned)(keys[row] & 0xffffffffull);
    const float zq = cb[(size_t)idx * DD + tid];
    const float hv = h[(size_t)row * DD + tid];
    out[(size_t)row * DD + tid] = zq;  // straight-through: h + (zq - h) == zq
    const float d = zq - hv;
    float s = d * d;
#pragma unroll
    for (int off = 32; off; off >>= 1) s += __shfl_down(s, off);
    __shared__ float wsum[4];
    if ((tid & 63) == 0) wsum[tid >> 6] = s;
    __syncthreads();
    if (tid == 0) atomicAdd(loss, (wsum[0] + wsum[1]) + (wsum[2] + wsum[3]));
}

__global__ void k_final(const float* __restrict__ loss, float* __restrict__ out) {
    // BETA*mean + mean = 1.25 * mean
    out[0] = 1.25f * (*loss) / (float)(M_TOT * DD);
}

// ---------------------------------------------------------------------------
extern "C" void kernel_launch(void* const* d_in, const int* in_sizes, int n_in,
                              void* d_out, int out_size, void* d_ws, size_t ws_size,
                              hipStream_t stream) {
    const float* x  = (const float*)d_in[0];  // [8,4096,1,512]
    const float* W  = (const float*)d_in[1];  // [512,256]
    const float* b  = (const float*)d_in[2];  // [256]
    const float* cb = (const float*)d_in[3];  // [8192,256]
    float* out = (float*)d_out;               // quant [32768*256] + loss [1]

    char* ws = (char*)d_ws;
    float* h  = (float*)(ws + OFF_H);
    float* hh = (float*)(ws + OFF_HH);
    float* ee = (float*)(ws + OFF_EE);
    unsigned long long* keys = (unsigned long long*)(ws + OFF_KEYS);
    float* loss = (float*)(ws + OFF_LOSS);

    hipLaunchKernelGGL(k_gemm1, dim3(DD / 64, M_TOT / 64), dim3(16, 16), 0, stream,
                       x, W, b, h);
    hipLaunchKernelGGL(k_rownorm, dim3(M_TOT), dim3(256), 0, stream, h, hh);
    hipLaunchKernelGGL(k_rownorm, dim3(KCODES), dim3(256), 0, stream, cb, ee);
    hipLaunchKernelGGL(k_init, dim3((M_TOT / 256) + 1), dim3(256), 0, stream, keys, loss);
    hipLaunchKernelGGL(k_dist_argmin, dim3(KCODES / 128, M_TOT / 128), dim3(16, 16),
                       0, stream, h, cb, hh, ee, keys);
    hipLaunchKernelGGL(k_gather_loss, dim3(M_TOT), dim3(256), 0, stream,
                       h, cb, keys, out, loss);
    hipLaunchKernelGGL(k_final, dim3(1), dim3(1), 0, stream,
                       loss, out + (size_t)M_TOT * DD);
}

// Round 2
// 1041.051 us; speedup vs baseline: 2.1196x; 2.1196x over previous
//
#include <hip/hip_runtime.h>
#include <hip/hip_bf16.h>
#include <stdint.h>

// Problem constants (B=8, T=4096, Zc=512, D=256, K=8192)
#define M_TOT 32768
#define ZC 512
#define DD 256
#define KCODES 8192
#define NGRAN 512            // KCODES / 16 codes per granule
#define MARGIN 0.15f         // >2x hard fp16-error bound (~0.05) + storage rounding

typedef _Float16 half8  __attribute__((ext_vector_type(8)));
typedef _Float16 half2v __attribute__((ext_vector_type(2)));
typedef float    float4v __attribute__((ext_vector_type(4)));

// Workspace layout (bytes)
#define OFF_H     0ull                 // h fp32: 32 MB
#define OFF_H16   33554432ull          // h fp16: 16 MB
#define OFF_CB16  50331648ull          // cb fp16: 4 MB
#define OFF_HH    54525952ull          // hh: 128 KB
#define OFF_EE    54657024ull          // ee: 32 KB
#define OFF_SMIN  54689792ull          // smin fp16 [M_TOT][NGRAN]: 32 MB
#define OFF_KEYS  88244224ull          // keys u64: 256 KB
#define OFF_LOSS  88506368ull          // loss f32

// async global->LDS, 16B per lane, LDS dst = wave-uniform base + lane*16
#define ASYNC_CP16(gp, lp)                                                     \
  __builtin_amdgcn_global_load_lds(                                            \
      (const __attribute__((address_space(1))) void*)(gp),                     \
      (__attribute__((address_space(3))) void*)(lp), 16, 0, 0)

static __device__ __forceinline__ int pkmin(int a, int b) {
    half2v x = __builtin_bit_cast(half2v, a);
    half2v y = __builtin_bit_cast(half2v, b);
    half2v r;
    r.x = (x.x < y.x) ? x.x : y.x;
    r.y = (x.y < y.y) ? x.y : y.y;
    return __builtin_bit_cast(int, r);
}

// ---------------------------------------------------------------------------
// K1: h[M,256] = x[M,512] @ W[512,256] + b  (fp32, 64x64 tile) + fp16 copy
// ---------------------------------------------------------------------------
__global__ __launch_bounds__(256) void k_gemm1(const float* __restrict__ x,
                                               const float* __restrict__ W,
                                               const float* __restrict__ b,
                                               float* __restrict__ h,
                                               _Float16* __restrict__ h16) {
    __shared__ float sA[16 * 68];
    __shared__ float sB[16 * 68];
    const int tx = threadIdx.x, ty = threadIdx.y;
    const int tid = ty * 16 + tx;
    const int m0 = blockIdx.y * 64;
    const int n0 = blockIdx.x * 64;

    const int lrowA = tid >> 2, kqA = tid & 3;
    const int kB = tid >> 4,   nqB = tid & 15;

    float acc[4][4] = {};

    for (int kb = 0; kb < ZC; kb += 16) {
        float4 va = *(const float4*)&x[(size_t)(m0 + lrowA) * ZC + kb + kqA * 4];
        float4 vb = *(const float4*)&W[(size_t)(kb + kB) * DD + n0 + nqB * 4];
        __syncthreads();
        sA[(kqA * 4 + 0) * 68 + lrowA] = va.x;
        sA[(kqA * 4 + 1) * 68 + lrowA] = va.y;
        sA[(kqA * 4 + 2) * 68 + lrowA] = va.z;
        sA[(kqA * 4 + 3) * 68 + lrowA] = va.w;
        sB[kB * 68 + nqB * 4 + 0] = vb.x;
        sB[kB * 68 + nqB * 4 + 1] = vb.y;
        sB[kB * 68 + nqB * 4 + 2] = vb.z;
        sB[kB * 68 + nqB * 4 + 3] = vb.w;
        __syncthreads();
#pragma unroll
        for (int k = 0; k < 16; ++k) {
            float4 a4 = *(const float4*)&sA[k * 68 + ty * 4];
            float4 b4 = *(const float4*)&sB[k * 68 + tx * 4];
            float av[4] = {a4.x, a4.y, a4.z, a4.w};
            float bv[4] = {b4.x, b4.y, b4.z, b4.w};
#pragma unroll
            for (int i = 0; i < 4; ++i)
#pragma unroll
                for (int j = 0; j < 4; ++j)
                    acc[i][j] = fmaf(av[i], bv[j], acc[i][j]);
        }
    }
#pragma unroll
    for (int i = 0; i < 4; ++i) {
        const size_t row = (size_t)(m0 + ty * 4 + i);
#pragma unroll
        for (int j = 0; j < 4; ++j) {
            const int n = n0 + tx * 4 + j;
            const float v = acc[i][j] + b[n];
            h[row * DD + n] = v;
            h16[row * DD + n] = (_Float16)v;
        }
    }
}

// ---------------------------------------------------------------------------
// Row squared-norms of h (one block per row)
// ---------------------------------------------------------------------------
__global__ __launch_bounds__(256) void k_rownorm(const float* __restrict__ a,
                                                 float* __restrict__ out) {
    const int row = blockIdx.x;
    const int tid = threadIdx.x;
    float v = a[(size_t)row * DD + tid];
    float s = v * v;
#pragma unroll
    for (int off = 32; off; off >>= 1) s += __shfl_down(s, off);
    __shared__ float wsum[4];
    if ((tid & 63) == 0) wsum[tid >> 6] = s;
    __syncthreads();
    if (tid == 0) out[row] = (wsum[0] + wsum[1]) + (wsum[2] + wsum[3]);
}

// ---------------------------------------------------------------------------
// Prep codebook: fp16 copy + squared norms + zero loss accumulator
// ---------------------------------------------------------------------------
__global__ __launch_bounds__(256) void k_prep_cb(const float* __restrict__ cb,
                                                 _Float16* __restrict__ cb16,
                                                 float* __restrict__ ee,
                                                 float* __restrict__ loss) {
    const int row = blockIdx.x;
    const int tid = threadIdx.x;
    const float v = cb[(size_t)row * DD + tid];
    cb16[(size_t)row * DD + tid] = (_Float16)v;
    float s = v * v;
#pragma unroll
    for (int off = 32; off; off >>= 1) s += __shfl_down(s, off);
    __shared__ float wsum[4];
    if ((tid & 63) == 0) wsum[tid >> 6] = s;
    __syncthreads();
    if (tid == 0) ee[row] = (wsum[0] + wsum[1]) + (wsum[2] + wsum[3]);
    if (row == 0 && tid == 0) *loss = 0.0f;
}

// ---------------------------------------------------------------------------
// Phase 1: fp16 MFMA "distance" GEMM in s-space (s = ee - 2*dot).
// 128x128 tile, BK=32, global_load_lds staging, 16x16x32 f16 MFMA.
// Epilogue: per-row min over each 16-code granule -> smin[row][granule] fp16.
// ---------------------------------------------------------------------------
__global__ __launch_bounds__(256) void k_dist_mfma(const _Float16* __restrict__ h16,
                                                   const _Float16* __restrict__ cb16,
                                                   const float* __restrict__ ee,
                                                   _Float16* __restrict__ smin) {
    __shared__ char smem[16384];
    char* sA = smem;          // [128 rows][32 halves], 64B rows
    char* sB = smem + 8192;

    const int tid = threadIdx.x;
    const int w = tid >> 6, lane = tid & 63;
    const int m0 = blockIdx.y * 128, c0 = blockIdx.x * 128;

    // staging: 8 chunks of 1KB (16 rows); wave w owns chunks 2w, 2w+1
    const int j0 = w * 2, j1 = w * 2 + 1;
    const int rload = lane >> 2, kq = lane & 3;
    const _Float16* gA0 = h16 + (size_t)(m0 + j0 * 16 + rload) * DD + kq * 8;
    const _Float16* gA1 = h16 + (size_t)(m0 + j1 * 16 + rload) * DD + kq * 8;
    const _Float16* gB0 = cb16 + (size_t)(c0 + j0 * 16 + rload) * DD + kq * 8;
    const _Float16* gB1 = cb16 + (size_t)(c0 + j1 * 16 + rload) * DD + kq * 8;
    char* lA0 = sA + j0 * 1024;
    char* lA1 = sA + j1 * 1024;
    char* lB0 = sB + j0 * 1024;
    char* lB1 = sB + j1 * 1024;

    const int col = lane & 15, quad = lane >> 4;
    const int wm = w >> 1, wn = w & 1;  // wave subtile (64x64) within 128x128

    float4v acc[4][4];
#pragma unroll
    for (int i = 0; i < 4; ++i)
#pragma unroll
        for (int j = 0; j < 4; ++j) acc[i][j] = (float4v){0.f, 0.f, 0.f, 0.f};

    for (int kb = 0; kb < DD; kb += 32) {
        ASYNC_CP16(gA0 + kb, lA0);
        ASYNC_CP16(gA1 + kb, lA1);
        ASYNC_CP16(gB0 + kb, lB0);
        ASYNC_CP16(gB1 + kb, lB1);
        __syncthreads();
        half8 af[4], bf[4];
#pragma unroll
        for (int i = 0; i < 4; ++i)
            af[i] = *(const half8*)(sA + ((wm * 64 + i * 16 + col) * 64 + quad * 16));
#pragma unroll
        for (int j = 0; j < 4; ++j)
            bf[j] = *(const half8*)(sB + ((wn * 64 + j * 16 + col) * 64 + quad * 16));
#pragma unroll
        for (int i = 0; i < 4; ++i)
#pragma unroll
            for (int j = 0; j < 4; ++j)
                acc[i][j] = __builtin_amdgcn_mfma_f32_16x16x32_f16(af[i], bf[j],
                                                                   acc[i][j], 0, 0, 0);
        __syncthreads();
    }

    // Epilogue: s = ee - 2*dot; per-row min across the 16 cols of each n-tile.
    float eev[4];
#pragma unroll
    for (int j = 0; j < 4; ++j) eev[j] = ee[c0 + wn * 64 + j * 16 + col];

#pragma unroll
    for (int i = 0; i < 4; ++i) {
        const int rowb = m0 + wm * 64 + i * 16 + quad * 4;
#pragma unroll
        for (int j = 0; j < 4; ++j) {
            const float4v a = acc[i][j];
            const float e = eev[j];
            half2v p0, p1;
            p0.x = (_Float16)(e - 2.0f * a.x);
            p0.y = (_Float16)(e - 2.0f * a.y);
            p1.x = (_Float16)(e - 2.0f * a.z);
            p1.y = (_Float16)(e - 2.0f * a.w);
            int b0 = __builtin_bit_cast(int, p0);
            int b1 = __builtin_bit_cast(int, p1);
#pragma unroll
            for (int m = 1; m <= 8; m <<= 1) {
                b0 = pkmin(b0, __shfl_xor(b0, m));
                b1 = pkmin(b1, __shfl_xor(b1, m));
            }
            const int g = blockIdx.x * 8 + wn * 4 + j;
            if (col == 0) {
                half2v r = __builtin_bit_cast(half2v, b0);
                smin[(size_t)(rowb + 0) * NGRAN + g] = r.x;
                smin[(size_t)(rowb + 1) * NGRAN + g] = r.y;
            } else if (col == 1) {
                half2v r = __builtin_bit_cast(half2v, b1);
                smin[(size_t)(rowb + 2) * NGRAN + g] = r.x;
                smin[(size_t)(rowb + 3) * NGRAN + g] = r.y;
            }
        }
    }
}

// ---------------------------------------------------------------------------
// Phase 2: per row, find granules within MARGIN of the stored min; rescore
// those codes exactly in fp32 with the reference formula (hh+ee)-2*dot;
// tie-break = lowest index via packed u64 key.
// ---------------------------------------------------------------------------
__global__ __launch_bounds__(256) void k_select(const float* __restrict__ h,
                                                const float* __restrict__ cb,
                                                const float* __restrict__ hh,
                                                const float* __restrict__ ee,
                                                const _Float16* __restrict__ smin,
                                                unsigned long long* __restrict__ keys) {
    const int row = blockIdx.x, t = threadIdx.x;
    __shared__ float wred[4];
    __shared__ float thr_s;
    __shared__ int cand[NGRAN];
    __shared__ int ncand;
    __shared__ unsigned long long bestk;
    if (t == 0) { ncand = 0; bestk = ~0ull; }

    const _Float16* sm = smin + (size_t)row * NGRAN;
    const float v0 = (float)sm[2 * t];
    const float v1 = (float)sm[2 * t + 1];
    float v = fminf(v0, v1);
#pragma unroll
    for (int off = 32; off; off >>= 1) v = fminf(v, __shfl_down(v, off));
    __syncthreads();
    if ((t & 63) == 0) wred[t >> 6] = v;
    __syncthreads();
    if (t == 0)
        thr_s = fminf(fminf(wred[0], wred[1]), fminf(wred[2], wred[3])) + MARGIN;
    __syncthreads();
    const float thr = thr_s;
    if (v0 <= thr) { int p = atomicAdd(&ncand, 1); cand[p] = 2 * t; }
    if (v1 <= thr) { int p = atomicAdd(&ncand, 1); cand[p] = 2 * t + 1; }

    // h chunk for this thread (chunk = t&15 fixed across candidates)
    const int chunk = t & 15, cl = t >> 4;
    float4v hv[4];
#pragma unroll
    for (int q = 0; q < 4; ++q)
        hv[q] = *(const float4v*)&h[(size_t)row * DD + chunk * 16 + q * 4];
    const float hhv = hh[row];
    __syncthreads();

    const int nc = ncand;
    for (int ci = 0; ci < nc; ++ci) {
        const int g = cand[ci];
        const int code = g * 16 + cl;
        const float* cp = &cb[(size_t)code * DD + chunk * 16];
        float s = 0.f;
#pragma unroll
        for (int q = 0; q < 4; ++q) {
            float4v c4 = *(const float4v*)(cp + q * 4);
            s = fmaf(hv[q].x, c4.x, s);
            s = fmaf(hv[q].y, c4.y, s);
            s = fmaf(hv[q].z, c4.z, s);
            s = fmaf(hv[q].w, c4.w, s);
        }
#pragma unroll
        for (int m = 1; m <= 8; m <<= 1) s += __shfl_xor(s, m);
        if (chunk == 0) {
            const float d = (hhv + ee[code]) - 2.0f * s;  // reference formula
            const unsigned bts = __float_as_uint(d);
            const unsigned mb = bts ^ (unsigned)(((int)bts >> 31) | 0x80000000);
            const unsigned long long key =
                ((unsigned long long)mb << 32) | (unsigned)code;
            atomicMin(&bestk, key);
        }
    }
    __syncthreads();
    if (t == 0) keys[row] = bestk;
}

// ---------------------------------------------------------------------------
// K3: gather zq, write quant output, accumulate sum((zq-h)^2)
// ---------------------------------------------------------------------------
__global__ __launch_bounds__(256) void k_gather_loss(const float* __restrict__ h,
                                                     const float* __restrict__ cb,
                                                     const unsigned long long* __restrict__ keys,
                                                     float* __restrict__ out,
                                                     float* __restrict__ loss) {
    const int row = blockIdx.x;
    const int tid = threadIdx.x;
    const unsigned idx = (unsigned)(keys[row] & 0xffffffffull);
    const float zq = cb[(size_t)idx * DD + tid];
    const float hv = h[(size_t)row * DD + tid];
    out[(size_t)row * DD + tid] = zq;  // straight-through: h + (zq - h) == zq
    const float d = zq - hv;
    float s = d * d;
#pragma unroll
    for (int off = 32; off; off >>= 1) s += __shfl_down(s, off);
    __shared__ float wsum[4];
    if ((tid & 63) == 0) wsum[tid >> 6] = s;
    __syncthreads();
    if (tid == 0) atomicAdd(loss, (wsum[0] + wsum[1]) + (wsum[2] + wsum[3]));
}

__global__ void k_final(const float* __restrict__ loss, float* __restrict__ out) {
    out[0] = 1.25f * (*loss) / (float)(M_TOT * DD);  // BETA*mean + mean
}

// ---------------------------------------------------------------------------
extern "C" void kernel_launch(void* const* d_in, const int* in_sizes, int n_in,
                              void* d_out, int out_size, void* d_ws, size_t ws_size,
                              hipStream_t stream) {
    const float* x  = (const float*)d_in[0];
    const float* W  = (const float*)d_in[1];
    const float* b  = (const float*)d_in[2];
    const float* cb = (const float*)d_in[3];
    float* out = (float*)d_out;

    char* ws = (char*)d_ws;
    float* h    = (float*)(ws + OFF_H);
    _Float16* h16  = (_Float16*)(ws + OFF_H16);
    _Float16* cb16 = (_Float16*)(ws + OFF_CB16);
    float* hh   = (float*)(ws + OFF_HH);
    float* ee   = (float*)(ws + OFF_EE);
    _Float16* smin = (_Float16*)(ws + OFF_SMIN);
    unsigned long long* keys = (unsigned long long*)(ws + OFF_KEYS);
    float* loss = (float*)(ws + OFF_LOSS);

    hipLaunchKernelGGL(k_gemm1, dim3(DD / 64, M_TOT / 64), dim3(16, 16), 0, stream,
                       x, W, b, h, h16);
    hipLaunchKernelGGL(k_rownorm, dim3(M_TOT), dim3(256), 0, stream, h, hh);
    hipLaunchKernelGGL(k_prep_cb, dim3(KCODES), dim3(256), 0, stream,
                       cb, cb16, ee, loss);
    hipLaunchKernelGGL(k_dist_mfma, dim3(KCODES / 128, M_TOT / 128), dim3(256),
                       0, stream, h16, cb16, ee, smin);
    hipLaunchKernelGGL(k_select, dim3(M_TOT), dim3(256), 0, stream,
                       h, cb, hh, ee, smin, keys);
    hipLaunchKernelGGL(k_gather_loss, dim3(M_TOT), dim3(256), 0, stream,
                       h, cb, keys, out, loss);
    hipLaunchKernelGGL(k_final, dim3(1), dim3(1), 0, stream,
                       loss, out + (size_t)M_TOT * DD);
}

// Round 3
// 577.959 us; speedup vs baseline: 3.8179x; 1.8013x over previous
//
#include <hip/hip_runtime.h>
#include <hip/hip_bf16.h>
#include <stdint.h>

// Problem constants (B=8, T=4096, Zc=512, D=256, K=8192)
#define M_TOT 32768
#define ZC 512
#define DD 256
#define KCODES 8192
#define NGRAN 512            // KCODES / 16 codes per granule
#define MARGIN 0.15f         // >2x hard fp16-error bound (~0.05) + storage rounding
#define NBUCKET 256          // loss atomic buckets

typedef _Float16 half8  __attribute__((ext_vector_type(8)));
typedef _Float16 half4v __attribute__((ext_vector_type(4)));
typedef _Float16 half2v __attribute__((ext_vector_type(2)));
typedef float    float4v __attribute__((ext_vector_type(4)));

// Workspace layout (bytes)
#define OFF_H     0ull                 // h fp32: 32 MB
#define OFF_H16   33554432ull          // h fp16: 16 MB
#define OFF_CB16  50331648ull          // cb fp16: 4 MB
#define OFF_HH    54525952ull          // hh: 128 KB
#define OFF_EE    54657024ull          // ee: 32 KB
#define OFF_SMIN  54689792ull          // smin fp16 [M_TOT][NGRAN]: 32 MB
#define OFF_LOSSP 88244224ull          // loss buckets: NBUCKET f32

// async global->LDS, 16B per lane, LDS dst = wave-uniform base + lane*16
#define ASYNC_CP16(gp, lp)                                                     \
  __builtin_amdgcn_global_load_lds(                                            \
      (const __attribute__((address_space(1))) void*)(gp),                     \
      (__attribute__((address_space(3))) void*)(lp), 16, 0, 0)

static __device__ __forceinline__ int pkmin(int a, int b) {
    half2v x = __builtin_bit_cast(half2v, a);
    half2v y = __builtin_bit_cast(half2v, b);
    half2v r;
    r.x = (x.x < y.x) ? x.x : y.x;
    r.y = (x.y < y.y) ? x.y : y.y;
    return __builtin_bit_cast(int, r);
}

// ---------------------------------------------------------------------------
// K1: h[M,256] = x[M,512] @ W[512,256] + b  (fp32, 64x64 tile) + fp16 copy
// ---------------------------------------------------------------------------
__global__ __launch_bounds__(256) void k_gemm1(const float* __restrict__ x,
                                               const float* __restrict__ W,
                                               const float* __restrict__ b,
                                               float* __restrict__ h,
                                               _Float16* __restrict__ h16) {
    __shared__ float sA[16 * 68];
    __shared__ float sB[16 * 68];
    const int tx = threadIdx.x, ty = threadIdx.y;
    const int tid = ty * 16 + tx;
    const int m0 = blockIdx.y * 64;
    const int n0 = blockIdx.x * 64;

    const int lrowA = tid >> 2, kqA = tid & 3;
    const int kB = tid >> 4,   nqB = tid & 15;

    float acc[4][4] = {};

    for (int kb = 0; kb < ZC; kb += 16) {
        float4 va = *(const float4*)&x[(size_t)(m0 + lrowA) * ZC + kb + kqA * 4];
        float4 vb = *(const float4*)&W[(size_t)(kb + kB) * DD + n0 + nqB * 4];
        __syncthreads();
        sA[(kqA * 4 + 0) * 68 + lrowA] = va.x;
        sA[(kqA * 4 + 1) * 68 + lrowA] = va.y;
        sA[(kqA * 4 + 2) * 68 + lrowA] = va.z;
        sA[(kqA * 4 + 3) * 68 + lrowA] = va.w;
        sB[kB * 68 + nqB * 4 + 0] = vb.x;
        sB[kB * 68 + nqB * 4 + 1] = vb.y;
        sB[kB * 68 + nqB * 4 + 2] = vb.z;
        sB[kB * 68 + nqB * 4 + 3] = vb.w;
        __syncthreads();
#pragma unroll
        for (int k = 0; k < 16; ++k) {
            float4 a4 = *(const float4*)&sA[k * 68 + ty * 4];
            float4 b4 = *(const float4*)&sB[k * 68 + tx * 4];
            float av[4] = {a4.x, a4.y, a4.z, a4.w};
            float bv[4] = {b4.x, b4.y, b4.z, b4.w};
#pragma unroll
            for (int i = 0; i < 4; ++i)
#pragma unroll
                for (int j = 0; j < 4; ++j)
                    acc[i][j] = fmaf(av[i], bv[j], acc[i][j]);
        }
    }
#pragma unroll
    for (int i = 0; i < 4; ++i) {
        const size_t row = (size_t)(m0 + ty * 4 + i);
#pragma unroll
        for (int j = 0; j < 4; ++j) {
            const int n = n0 + tx * 4 + j;
            const float v = acc[i][j] + b[n];
            h[row * DD + n] = v;
            h16[row * DD + n] = (_Float16)v;
        }
    }
}

// ---------------------------------------------------------------------------
// Row squared-norms, wave-per-row (4 rows/block, float4, shuffle-only)
// ---------------------------------------------------------------------------
__global__ __launch_bounds__(256) void k_rownorm(const float* __restrict__ a,
                                                 float* __restrict__ out) {
    const int w = threadIdx.x >> 6, lane = threadIdx.x & 63;
    const int row = blockIdx.x * 4 + w;
    float4v v = *(const float4v*)&a[(size_t)row * DD + lane * 4];
    float s = v.x * v.x + v.y * v.y + v.z * v.z + v.w * v.w;
#pragma unroll
    for (int off = 32; off; off >>= 1) s += __shfl_down(s, off);
    if (lane == 0) out[row] = s;
}

// ---------------------------------------------------------------------------
// Prep codebook: fp16 copy + squared norms, wave-per-row; block0 zeroes buckets
// ---------------------------------------------------------------------------
__global__ __launch_bounds__(256) void k_prep_cb(const float* __restrict__ cb,
                                                 _Float16* __restrict__ cb16,
                                                 float* __restrict__ ee,
                                                 float* __restrict__ loss_part) {
    if (blockIdx.x == 0) loss_part[threadIdx.x] = 0.0f;
    const int w = threadIdx.x >> 6, lane = threadIdx.x & 63;
    const int row = blockIdx.x * 4 + w;
    float4v v = *(const float4v*)&cb[(size_t)row * DD + lane * 4];
    half4v hv;
    hv.x = (_Float16)v.x; hv.y = (_Float16)v.y;
    hv.z = (_Float16)v.z; hv.w = (_Float16)v.w;
    *(half4v*)&cb16[(size_t)row * DD + lane * 4] = hv;
    float s = v.x * v.x + v.y * v.y + v.z * v.z + v.w * v.w;
#pragma unroll
    for (int off = 32; off; off >>= 1) s += __shfl_down(s, off);
    if (lane == 0) ee[row] = s;
}

// ---------------------------------------------------------------------------
// Phase 1: fp16 MFMA "distance" GEMM in s-space (s = ee - 2*dot).
// 128x128 tile, BK=32, global_load_lds staging, 16x16x32 f16 MFMA.
// Epilogue: per-row min over each 16-code granule -> smin[row][granule] fp16.
// ---------------------------------------------------------------------------
__global__ __launch_bounds__(256) void k_dist_mfma(const _Float16* __restrict__ h16,
                                                   const _Float16* __restrict__ cb16,
                                                   const float* __restrict__ ee,
                                                   _Float16* __restrict__ smin) {
    __shared__ char smem[16384];
    char* sA = smem;          // [128 rows][32 halves], 64B rows
    char* sB = smem + 8192;

    const int tid = threadIdx.x;
    const int w = tid >> 6, lane = tid & 63;
    const int m0 = blockIdx.y * 128, c0 = blockIdx.x * 128;

    // staging: 8 chunks of 1KB (16 rows); wave w owns chunks 2w, 2w+1
    const int j0 = w * 2, j1 = w * 2 + 1;
    const int rload = lane >> 2, kq = lane & 3;
    const _Float16* gA0 = h16 + (size_t)(m0 + j0 * 16 + rload) * DD + kq * 8;
    const _Float16* gA1 = h16 + (size_t)(m0 + j1 * 16 + rload) * DD + kq * 8;
    const _Float16* gB0 = cb16 + (size_t)(c0 + j0 * 16 + rload) * DD + kq * 8;
    const _Float16* gB1 = cb16 + (size_t)(c0 + j1 * 16 + rload) * DD + kq * 8;
    char* lA0 = sA + j0 * 1024;
    char* lA1 = sA + j1 * 1024;
    char* lB0 = sB + j0 * 1024;
    char* lB1 = sB + j1 * 1024;

    const int col = lane & 15, quad = lane >> 4;
    const int wm = w >> 1, wn = w & 1;  // wave subtile (64x64) within 128x128

    float4v acc[4][4];
#pragma unroll
    for (int i = 0; i < 4; ++i)
#pragma unroll
        for (int j = 0; j < 4; ++j) acc[i][j] = (float4v){0.f, 0.f, 0.f, 0.f};

    for (int kb = 0; kb < DD; kb += 32) {
        ASYNC_CP16(gA0 + kb, lA0);
        ASYNC_CP16(gA1 + kb, lA1);
        ASYNC_CP16(gB0 + kb, lB0);
        ASYNC_CP16(gB1 + kb, lB1);
        __syncthreads();
        half8 af[4], bf[4];
#pragma unroll
        for (int i = 0; i < 4; ++i)
            af[i] = *(const half8*)(sA + ((wm * 64 + i * 16 + col) * 64 + quad * 16));
#pragma unroll
        for (int j = 0; j < 4; ++j)
            bf[j] = *(const half8*)(sB + ((wn * 64 + j * 16 + col) * 64 + quad * 16));
#pragma unroll
        for (int i = 0; i < 4; ++i)
#pragma unroll
            for (int j = 0; j < 4; ++j)
                acc[i][j] = __builtin_amdgcn_mfma_f32_16x16x32_f16(af[i], bf[j],
                                                                   acc[i][j], 0, 0, 0);
        __syncthreads();
    }

    // Epilogue: s = ee - 2*dot; per-row min across the 16 cols of each n-tile.
    float eev[4];
#pragma unroll
    for (int j = 0; j < 4; ++j) eev[j] = ee[c0 + wn * 64 + j * 16 + col];

#pragma unroll
    for (int i = 0; i < 4; ++i) {
        const int rowb = m0 + wm * 64 + i * 16 + quad * 4;
#pragma unroll
        for (int j = 0; j < 4; ++j) {
            const float4v a = acc[i][j];
            const float e = eev[j];
            half2v p0, p1;
            p0.x = (_Float16)(e - 2.0f * a.x);
            p0.y = (_Float16)(e - 2.0f * a.y);
            p1.x = (_Float16)(e - 2.0f * a.z);
            p1.y = (_Float16)(e - 2.0f * a.w);
            int b0 = __builtin_bit_cast(int, p0);
            int b1 = __builtin_bit_cast(int, p1);
#pragma unroll
            for (int m = 1; m <= 8; m <<= 1) {
                b0 = pkmin(b0, __shfl_xor(b0, m));
                b1 = pkmin(b1, __shfl_xor(b1, m));
            }
            const int g = blockIdx.x * 8 + wn * 4 + j;
            if (col == 0) {
                half2v r = __builtin_bit_cast(half2v, b0);
                smin[(size_t)(rowb + 0) * NGRAN + g] = r.x;
                smin[(size_t)(rowb + 1) * NGRAN + g] = r.y;
            } else if (col == 1) {
                half2v r = __builtin_bit_cast(half2v, b1);
                smin[(size_t)(rowb + 2) * NGRAN + g] = r.x;
                smin[(size_t)(rowb + 3) * NGRAN + g] = r.y;
            }
        }
    }
}

// ---------------------------------------------------------------------------
// Phase 2 (fused): per row — margin-filter granules, fp32 rescore with the
// reference formula (hh+ee)-2*dot, argmin w/ lowest-index tie-break, then
// gather zq, write quant, and accumulate loss into 256 atomic buckets.
// ---------------------------------------------------------------------------
__global__ __launch_bounds__(256) void k_select_out(const float* __restrict__ h,
                                                    const float* __restrict__ cb,
                                                    const float* __restrict__ hh,
                                                    const float* __restrict__ ee,
                                                    const _Float16* __restrict__ smin,
                                                    float* __restrict__ out,
                                                    float* __restrict__ loss_part) {
    const int row = blockIdx.x, t = threadIdx.x;
    __shared__ float wred[4];
    __shared__ float thr_s;
    __shared__ int cand[NGRAN];
    __shared__ int ncand;
    __shared__ unsigned long long bestk;
    if (t == 0) { ncand = 0; bestk = ~0ull; }

    // --- threshold from granule mins (vectorized half2 read) ---
    const half2v p = *(const half2v*)(smin + (size_t)row * NGRAN + 2 * t);
    const float v0 = (float)p.x, v1 = (float)p.y;
    float v = fminf(v0, v1);
#pragma unroll
    for (int off = 32; off; off >>= 1) v = fminf(v, __shfl_down(v, off));
    __syncthreads();
    if ((t & 63) == 0) wred[t >> 6] = v;
    __syncthreads();
    if (t == 0)
        thr_s = fminf(fminf(wred[0], wred[1]), fminf(wred[2], wred[3])) + MARGIN;
    __syncthreads();
    const float thr = thr_s;
    if (v0 <= thr) { int q = atomicAdd(&ncand, 1); cand[q] = 2 * t; }
    if (v1 <= thr) { int q = atomicAdd(&ncand, 1); cand[q] = 2 * t + 1; }

    // --- exact fp32 rescore of candidate granules ---
    const int chunk = t & 15, cl = t >> 4;
    float4v hv[4];
#pragma unroll
    for (int q = 0; q < 4; ++q)
        hv[q] = *(const float4v*)&h[(size_t)row * DD + chunk * 16 + q * 4];
    const float hhv = hh[row];
    __syncthreads();

    const int nc = ncand;
    for (int ci = 0; ci < nc; ++ci) {
        const int g = cand[ci];
        const int code = g * 16 + cl;
        const float* cp = &cb[(size_t)code * DD + chunk * 16];
        float s = 0.f;
#pragma unroll
        for (int q = 0; q < 4; ++q) {
            float4v c4 = *(const float4v*)(cp + q * 4);
            s = fmaf(hv[q].x, c4.x, s);
            s = fmaf(hv[q].y, c4.y, s);
            s = fmaf(hv[q].z, c4.z, s);
            s = fmaf(hv[q].w, c4.w, s);
        }
#pragma unroll
        for (int m = 1; m <= 8; m <<= 1) s += __shfl_xor(s, m);
        if (chunk == 0) {
            const float d = (hhv + ee[code]) - 2.0f * s;  // reference formula
            const unsigned bts = __float_as_uint(d);
            const unsigned mb = bts ^ (unsigned)(((int)bts >> 31) | 0x80000000);
            const unsigned long long key =
                ((unsigned long long)mb << 32) | (unsigned)code;
            atomicMin(&bestk, key);
        }
    }
    __syncthreads();

    // --- gather + output + loss ---
    const unsigned best = (unsigned)(bestk & 0xffffffffull);
    const float zq = cb[(size_t)best * DD + t];
    const float he = h[(size_t)row * DD + t];
    out[(size_t)row * DD + t] = zq;  // straight-through: h + sg(zq-h) == zq
    const float dd = zq - he;
    float s2 = dd * dd;
#pragma unroll
    for (int off = 32; off; off >>= 1) s2 += __shfl_down(s2, off);
    __syncthreads();
    if ((t & 63) == 0) wred[t >> 6] = s2;
    __syncthreads();
    if (t == 0)
        atomicAdd(&loss_part[row & (NBUCKET - 1)],
                  (wred[0] + wred[1]) + (wred[2] + wred[3]));
}

__global__ __launch_bounds__(256) void k_final(const float* __restrict__ loss_part,
                                               float* __restrict__ out) {
    const int t = threadIdx.x;
    float s = loss_part[t];
#pragma unroll
    for (int off = 32; off; off >>= 1) s += __shfl_down(s, off);
    __shared__ float wsum[4];
    if ((t & 63) == 0) wsum[t >> 6] = s;
    __syncthreads();
    if (t == 0)
        out[0] = 1.25f * ((wsum[0] + wsum[1]) + (wsum[2] + wsum[3]))
                 / (float)(M_TOT * DD);  // BETA*mean + mean
}

// ---------------------------------------------------------------------------
extern "C" void kernel_launch(void* const* d_in, const int* in_sizes, int n_in,
                              void* d_out, int out_size, void* d_ws, size_t ws_size,
                              hipStream_t stream) {
    const float* x  = (const float*)d_in[0];
    const float* W  = (const float*)d_in[1];
    const float* b  = (const float*)d_in[2];
    const float* cb = (const float*)d_in[3];
    float* out = (float*)d_out;

    char* ws = (char*)d_ws;
    float* h    = (float*)(ws + OFF_H);
    _Float16* h16  = (_Float16*)(ws + OFF_H16);
    _Float16* cb16 = (_Float16*)(ws + OFF_CB16);
    float* hh   = (float*)(ws + OFF_HH);
    float* ee   = (float*)(ws + OFF_EE);
    _Float16* smin = (_Float16*)(ws + OFF_SMIN);
    float* loss_part = (float*)(ws + OFF_LOSSP);

    hipLaunchKernelGGL(k_gemm1, dim3(DD / 64, M_TOT / 64), dim3(16, 16), 0, stream,
                       x, W, b, h, h16);
    hipLaunchKernelGGL(k_rownorm, dim3(M_TOT / 4), dim3(256), 0, stream, h, hh);
    hipLaunchKernelGGL(k_prep_cb, dim3(KCODES / 4), dim3(256), 0, stream,
                       cb, cb16, ee, loss_part);
    hipLaunchKernelGGL(k_dist_mfma, dim3(KCODES / 128, M_TOT / 128), dim3(256),
                       0, stream, h16, cb16, ee, smin);
    hipLaunchKernelGGL(k_select_out, dim3(M_TOT), dim3(256), 0, stream,
                       h, cb, hh, ee, smin, out, loss_part);
    hipLaunchKernelGGL(k_final, dim3(1), dim3(256), 0, stream,
                       loss_part, out + (size_t)M_TOT * DD);
}